// Round 7
// baseline (351.909 us; speedup 1.0000x reference)
//
#include <hip/hip_runtime.h>
#include <stdint.h>

typedef _Float16 f16x8 __attribute__((ext_vector_type(8)));
typedef float    f32x4 __attribute__((ext_vector_type(4)));

union FragU { unsigned u[4]; f16x8 h; };

__device__ __forceinline__ unsigned pkh(float a, float b) {
    return __builtin_bit_cast(unsigned, __builtin_amdgcn_cvt_pkrtz(a, b));
}

#define MFMA(A, B, C) __builtin_amdgcn_mfma_f32_16x16x32_f16((A).h, (B).h, (C), 0, 0, 0)

#define K1 (-1.5339807878856412e-03f)   /* -2*pi/4096 */
#define K2 (-2.4543692606170259e-02f)   /* -2*pi/256  */

// Wave-per-row, ZERO barriers. 4096-pt FFT = 3 radix-16 stages as complex
// 16x16 GEMMs (mfma_f32_16x16x32_f16, K=32 stacking). One 64-thread block
// (one wave) per (b,h) row; all LDS is wave-private, ordering by in-wave
// program order + compiler lgkmcnt. Stages 2+3 fused per tile via a 1KB
// slab; stage-3 outputs stored directly as paired 16B nt-stores (adjacent
// m1 pair -> contiguous float4), relying on L2 write-back line merging.
// LDS/wave = 16KB (stage-1 halves) + 1KB slab -> 9 waves/CU, all independent.
__global__ __launch_bounds__(64) void fft4096_wave(
    const float* __restrict__ xre, const float* __restrict__ xim,
    const float* __restrict__ mat16, float* __restrict__ out, int H)
{
    __shared__ __align__(16) unsigned char smem[17408];
    // bytes [0,8192): stage-1 re halves; [8192,16384): im halves;
    // [16384,17408): slab, 256 u32 (16x16 half2)

    const int l = threadIdx.x;       // 0..63
    const int g = l >> 4, c = l & 15;
    const int bh = blockIdx.x;
    const int h  = bh % H;
    const size_t base = (size_t)bh * 4096;

    // ---- M fragments (loaded once, reused by all 3 stages) ----
    const float* Mb = mat16 + (size_t)h * 512 + (size_t)c * 32 + g * 8;
    const float4 mf0 = *(const float4*)Mb;
    const float4 mf1 = *(const float4*)(Mb + 4);
    const unsigned mrA = pkh(mf0.x, mf0.z), mrB = pkh(mf1.x, mf1.z);
    const unsigned miA = pkh(mf0.y, mf0.w), miB = pkh(mf1.y, mf1.w);
    const unsigned nmiA = miA ^ 0x80008000u, nmiB = miB ^ 0x80008000u;

    FragU Afrag;  // A = [Mr | Mi] (stages 1,2)
    Afrag.u[0] = mrA; Afrag.u[1] = mrB; Afrag.u[2] = miA; Afrag.u[3] = miB;
    FragU BMr;    // stage3 B for Vr^T: [Mr^T ; -Mi^T]
    BMr.u[0] = mrA; BMr.u[1] = mrB; BMr.u[2] = nmiA; BMr.u[3] = nmiB;
    FragU BMi;    // stage3 B for Vi^T: [Mi^T ; Mr^T]
    BMi.u[0] = miA; BMi.u[1] = miB; BMi.u[2] = mrA; BMi.u[3] = mrB;

    const f32x4 zero = {0.f, 0.f, 0.f, 0.f};

    // stage-2 twiddle tw256(n2*m2): n2=c, m2=4g+reg (reused for all 16 tiles)
    float twc[4], tws[4];
    {
        float sb, cb, ss, cs;
        __sincosf(K2 * (float)(c * 4 * g), &sb, &cb);
        __sincosf(K2 * (float)c, &ss, &cs);
#pragma unroll
        for (int reg = 0; reg < 4; ++reg) {
            twc[reg] = cb; tws[reg] = sb;
            const float nc = cb * cs - sb * ss;
            const float ns = cb * ss + sb * cs;
            cb = nc; sb = ns;
        }
    }

    // ================= stage 1: Y1[m1][j] = sum_o M[m1][o] x[o*256+j] =========
    // 16 column-tiles, processed in 4 chunks of 4 (chunk q -> o2 block q).
#pragma unroll
    for (int q = 0; q < 4; ++q) {
        f32x4 s1r[4], s1i[4];
#pragma unroll
        for (int p = 0; p < 4; ++p) {
            const int col = (4 * q + p) * 16 + c;
            float xr[4], xi[4];
#pragma unroll
            for (int jj = 0; jj < 4; ++jj) {
                xr[jj] = xre[base + (size_t)((4 * g + jj) * 256 + col)];
                xi[jj] = xim[base + (size_t)((4 * g + jj) * 256 + col)];
            }
            const unsigned rp0 = pkh(xr[0], xr[1]), rp1 = pkh(xr[2], xr[3]);
            const unsigned ip0 = pkh(xi[0], xi[1]), ip1 = pkh(xi[2], xi[3]);
            const unsigned np0 = pkh(-xi[0], -xi[1]), np1 = pkh(-xi[2], -xi[3]);
            FragU Br; Br.u[0] = rp0; Br.u[1] = rp1; Br.u[2] = np0; Br.u[3] = np1;
            FragU Bi; Bi.u[0] = ip0; Bi.u[1] = ip1; Bi.u[2] = rp0; Bi.u[3] = rp1;
            s1r[p] = MFMA(Afrag, Br, zero);
            s1i[p] = MFMA(Afrag, Bi, zero);
        }
        // twiddle tw4096(j*m1), m1 = 4g+reg
#pragma unroll
        for (int p = 0; p < 4; ++p) {
            const int j = (4 * q + p) * 16 + c;
            float sb, cb, ss, cs;
            __sincosf(K1 * (float)(j * 4 * g), &sb, &cb);
            __sincosf(K1 * (float)j, &ss, &cs);
#pragma unroll
            for (int reg = 0; reg < 4; ++reg) {
                const float yr = s1r[p][reg], yi = s1i[p][reg];
                s1r[p][reg] = yr * cb - yi * sb;
                s1i[p][reg] = yr * sb + yi * cb;
                const float nc = cb * cs - sb * ss;
                const float ns = cb * ss + sb * cs;
                cb = nc; sb = ns;
            }
        }
        // LDS1 [m1][o3=c][o2], o2-chunk q stored at slot (q ^ (c>>2) ^ (m1&3))
#pragma unroll
        for (int reg = 0; reg < 4; ++reg) {
            const int m1 = 4 * g + reg;
            const int half = m1 * 256 + c * 16 + 4 * ((q ^ (c >> 2) ^ reg) & 3);
            uint2 vr, vi;
            vr.x = pkh(s1r[0][reg], s1r[1][reg]); vr.y = pkh(s1r[2][reg], s1r[3][reg]);
            vi.x = pkh(s1i[0][reg], s1i[1][reg]); vi.y = pkh(s1i[2][reg], s1i[3][reg]);
            *(uint2*)(smem + half * 2)        = vr;
            *(uint2*)(smem + 8192 + half * 2) = vi;
        }
    }
    // no barrier: wave-private LDS, in-wave program order suffices

    // ============ stages 2+3 fused per tile, tiles paired for 16B stores =====
    unsigned* slab = (unsigned*)(smem + 16384);
    float* __restrict__ og = out + 2 * base;   // float2 row base, as float*

#pragma unroll
    for (int mp = 0; mp < 8; ++mp) {
        f32x4 R0, I0, R1, I1;
#pragma unroll
        for (int s = 0; s < 2; ++s) {
            const int m1 = 2 * mp + s;
            // stage 2: B from LDS1 (chunk-permuted), A = [Mr|Mi]
            const int half = m1 * 256 + c * 16 + 4 * ((g ^ (c >> 2) ^ (m1 & 3)) & 3);
            const uint2 rp = *(const uint2*)(smem + half * 2);
            const uint2 ip = *(const uint2*)(smem + 8192 + half * 2);
            FragU Br; Br.u[0] = rp.x; Br.u[1] = rp.y;
            Br.u[2] = ip.x ^ 0x80008000u; Br.u[3] = ip.y ^ 0x80008000u;
            FragU Bi; Bi.u[0] = ip.x; Bi.u[1] = ip.y; Bi.u[2] = rp.x; Bi.u[3] = rp.y;
            f32x4 s2r = MFMA(Afrag, Br, zero);
            f32x4 s2i = MFMA(Afrag, Bi, zero);
#pragma unroll
            for (int reg = 0; reg < 4; ++reg) {
                const float yr = s2r[reg], yi = s2i[reg];
                s2r[reg] = yr * twc[reg] - yi * tws[reg];
                s2i[reg] = yr * tws[reg] + yi * twc[reg];
            }
            // slab write: [m2][n2] half2, phys = idx ^ (g<<2) ^ ((g&1)<<4)
            //  (XOR key recoverable from idx bits 6-7 on the read side)
#pragma unroll
            for (int reg = 0; reg < 4; ++reg) {
                const int idx = (4 * g + reg) * 16 + c;
                const int ph  = idx ^ (g << 2) ^ ((g & 1) << 4);
                slab[ph] = pkh(s2r[reg], s2i[reg]);
            }
            // slab read: A-frag row m2=c, k=n2=4g+jj (uint4 = 4 half2)
            {
                const int rb  = c * 16 + 4 * g;
                const int rph = rb ^ ((c >> 2) << 2) ^ (((c >> 2) & 1) << 4);
                const uint4 wv = *(const uint4*)(slab + rph);
                FragU Aup;
                Aup.u[0] = __builtin_amdgcn_perm(wv.y, wv.x, 0x05040100u);
                Aup.u[1] = __builtin_amdgcn_perm(wv.w, wv.z, 0x05040100u);
                Aup.u[2] = __builtin_amdgcn_perm(wv.y, wv.x, 0x07060302u);
                Aup.u[3] = __builtin_amdgcn_perm(wv.w, wv.z, 0x07060302u);
                const f32x4 vr3 = MFMA(Aup, BMr, zero);
                const f32x4 vi3 = MFMA(Aup, BMi, zero);
                if (s == 0) { R0 = vr3; I0 = vi3; } else { R1 = vr3; I1 = vi3; }
            }
        }
        // direct paired store: complex k = c*256 + (4g+reg)*16 + {2mp, 2mp+1}
#pragma unroll
        for (int reg = 0; reg < 4; ++reg) {
            const int k0 = c * 256 + (4 * g + reg) * 16 + 2 * mp;
            const f32x4 v = {R0[reg], I0[reg], R1[reg], I1[reg]};
            __builtin_nontemporal_store(v, (f32x4*)(og + 2 * k0));
        }
    }
}

extern "C" void kernel_launch(void* const* d_in, const int* in_sizes, int n_in,
                              void* d_out, int out_size, void* d_ws, size_t ws_size,
                              hipStream_t stream)
{
    const float* xre = (const float*)d_in[0];
    const float* xim = (const float*)d_in[1];
    const float* m16 = (const float*)d_in[5];   // (H,16,16,2) fp32
    const int H  = in_sizes[5] / 512;
    const int BH = in_sizes[0] / 4096;
    fft4096_wave<<<dim3(BH), dim3(64), 0, stream>>>(
        xre, xim, m16, (float*)d_out, H);
}

// Round 8
// 47.062 us; speedup vs baseline: 7.4776x; 7.4776x over previous
//
#include <hip/hip_runtime.h>
#include <stdint.h>

typedef _Float16 f16x8 __attribute__((ext_vector_type(8)));
typedef float    f32x4 __attribute__((ext_vector_type(4)));

union FragU { unsigned u[4]; f16x8 h; };

__device__ __forceinline__ unsigned pkh(float a, float b) {
    return __builtin_bit_cast(unsigned, __builtin_amdgcn_cvt_pkrtz(a, b));
}
__device__ __forceinline__ unsigned short h16(float a) {
    return __builtin_bit_cast(unsigned short, (_Float16)a);
}

#define MFMA(A, B, C) __builtin_amdgcn_mfma_f32_16x16x32_f16((A).h, (B).h, (C), 0, 0, 0)

#define K1 (-1.5339807878856412e-03f)   /* -2*pi/4096 */
#define K2 (-2.4543692606170259e-02f)   /* -2*pi/256  */

// 4096-pt FFT = 3 radix-16 stages; each stage = complex 16x16 GEMM via
// mfma_f32_16x16x32_f16 (K=32 stacking). One block per (b,h) row, 4 waves.
// Round-6 structure (best: 47.3us) + deep load issue:
//   __launch_bounds__(256,4) -> 128 VGPR budget; all 64 stage-1 dword loads
//   hoisted into registers before any convert/MFMA (64-deep MLP per wave).
// LDS (32 KiB total):
//   LDS1 [m1][o3][o2] fp16 halves @0/@8192   (stage1 -> stage2)
//   LDS2 [m2][m1][o3] fp16 halves @16384/@24576, XOR-swizzled (stage2 -> 3)
//   F    [n3][(m2,m1)^swz] float2, overlays everything (output transpose)
__global__ __launch_bounds__(256, 4) void fft4096_mfma(
    const float* __restrict__ xre, const float* __restrict__ xim,
    const float* __restrict__ mat16, float* __restrict__ out, int H)
{
    __shared__ __align__(16) unsigned char smem[32768];

    const int t = threadIdx.x;
    const int w = t >> 6;          // wave 0..3
    const int l = t & 63;
    const int g = l >> 4;          // lane group 0..3
    const int c = l & 15;          // lane col 0..15
    const int bh = blockIdx.x;
    const int h  = bh % H;
    const size_t base = (size_t)bh * 4096;

    // ---- all 64 stage-1 input loads issued FIRST (deep MLP) ----
    float xr[4][4], xi[4][4];
#pragma unroll
    for (int p = 0; p < 4; ++p) {
        const int col = (4 * w + p) * 16 + c;
#pragma unroll
        for (int jj = 0; jj < 4; ++jj) {
            xr[p][jj] = xre[base + (size_t)((4 * g + jj) * 256 + col)];
            xi[p][jj] = xim[base + (size_t)((4 * g + jj) * 256 + col)];
        }
    }

    // ---- M fragments (one load, reused by all 3 stages) ----
    const float* Mb = mat16 + (size_t)h * 512 + (size_t)c * 32 + g * 8;
    const float4 mf0 = *(const float4*)Mb;
    const float4 mf1 = *(const float4*)(Mb + 4);
    const unsigned mrA = pkh(mf0.x, mf0.z), mrB = pkh(mf1.x, mf1.z);
    const unsigned miA = pkh(mf0.y, mf0.w), miB = pkh(mf1.y, mf1.w);
    const unsigned nmiA = miA ^ 0x80008000u, nmiB = miB ^ 0x80008000u;

    FragU Afrag;  // A = [Mr | Mi] (stages 1,2)
    Afrag.u[0] = mrA; Afrag.u[1] = mrB; Afrag.u[2] = miA; Afrag.u[3] = miB;
    FragU BMr;    // stage3 B for Vr^T: [Mr^T ; -Mi^T]
    BMr.u[0] = mrA; BMr.u[1] = mrB; BMr.u[2] = nmiA; BMr.u[3] = nmiB;
    FragU BMi;    // stage3 B for Vi^T: [Mi^T ; Mr^T]
    BMi.u[0] = miA; BMi.u[1] = miB; BMi.u[2] = mrA; BMi.u[3] = mrB;

    const f32x4 zero = {0.f, 0.f, 0.f, 0.f};

    // ================= stage 1: Y1[m1][j] = sum_o M[m1][o] x[o*256+j] =========
    f32x4 s1r[4], s1i[4];
#pragma unroll
    for (int p = 0; p < 4; ++p) {
        const unsigned rp0 = pkh(xr[p][0], xr[p][1]), rp1 = pkh(xr[p][2], xr[p][3]);
        const unsigned ip0 = pkh(xi[p][0], xi[p][1]), ip1 = pkh(xi[p][2], xi[p][3]);
        const unsigned np0 = ip0 ^ 0x80008000u, np1 = ip1 ^ 0x80008000u;
        FragU Br; Br.u[0] = rp0; Br.u[1] = rp1; Br.u[2] = np0; Br.u[3] = np1;
        FragU Bi; Bi.u[0] = ip0; Bi.u[1] = ip1; Bi.u[2] = rp0; Bi.u[3] = rp1;
        s1r[p] = MFMA(Afrag, Br, zero);
        s1i[p] = MFMA(Afrag, Bi, zero);
    }
    // twiddle tw4096(j*m1), m1 = 4g+reg
#pragma unroll
    for (int p = 0; p < 4; ++p) {
        const int j = (4 * w + p) * 16 + c;
        float sb, cb, ss, cs;
        __sincosf(K1 * (float)(j * 4 * g), &sb, &cb);
        __sincosf(K1 * (float)j, &ss, &cs);
#pragma unroll
        for (int reg = 0; reg < 4; ++reg) {
            const float yr = s1r[p][reg], yi = s1i[p][reg];
            s1r[p][reg] = yr * cb - yi * sb;
            s1i[p][reg] = yr * sb + yi * cb;
            const float nc = cb * cs - sb * ss;
            const float ns = cb * ss + sb * cs;
            cb = nc; sb = ns;
        }
    }
    // LDS1 [m1][o3][o2], o2-block XOR-swizzled: s = (w ^ (c>>2) ^ reg) & 3
#pragma unroll
    for (int reg = 0; reg < 4; ++reg) {
        const int m1 = 4 * g + reg;
        const int half = m1 * 256 + c * 16 + 4 * ((w ^ (c >> 2) ^ reg) & 3);
        uint2 vr, vi;
        vr.x = pkh(s1r[0][reg], s1r[1][reg]); vr.y = pkh(s1r[2][reg], s1r[3][reg]);
        vi.x = pkh(s1i[0][reg], s1i[1][reg]); vi.y = pkh(s1i[2][reg], s1i[3][reg]);
        *(uint2*)(smem + half * 2)        = vr;
        *(uint2*)(smem + 8192 + half * 2) = vi;
    }
    __syncthreads();

    // ================= stage 2: A2[m2][o3] = sum_o2 M[m2][o2] T[o2*16+o3] =====
    f32x4 s2r[4], s2i[4];
#pragma unroll
    for (int p = 0; p < 4; ++p) {
        const int m1 = 4 * w + p;                  // tile = m1
        const int half = m1 * 256 + c * 16 + 4 * ((g ^ (c >> 2) ^ p) & 3);
        const uint2 rp = *(const uint2*)(smem + half * 2);
        const uint2 ip = *(const uint2*)(smem + 8192 + half * 2);
        FragU Br; Br.u[0] = rp.x; Br.u[1] = rp.y;
        Br.u[2] = ip.x ^ 0x80008000u; Br.u[3] = ip.y ^ 0x80008000u;
        FragU Bi; Bi.u[0] = ip.x; Bi.u[1] = ip.y; Bi.u[2] = rp.x; Bi.u[3] = rp.y;
        s2r[p] = MFMA(Afrag, Br, zero);
        s2i[p] = MFMA(Afrag, Bi, zero);
    }
    // tw256(o3*m2): o3=c, m2=4g+reg
    float twc[4], tws[4];
    {
        float sb, cb, ss, cs;
        __sincosf(K2 * (float)(c * 4 * g), &sb, &cb);
        __sincosf(K2 * (float)c, &ss, &cs);
#pragma unroll
        for (int reg = 0; reg < 4; ++reg) {
            twc[reg] = cb; tws[reg] = sb;
            const float nc = cb * cs - sb * ss;
            const float ns = cb * ss + sb * cs;
            cb = nc; sb = ns;
        }
    }
#pragma unroll
    for (int p = 0; p < 4; ++p) {
#pragma unroll
        for (int reg = 0; reg < 4; ++reg) {
            const float yr = s2r[p][reg], yi = s2i[p][reg];
            s2r[p][reg] = yr * twc[reg] - yi * tws[reg];
            s2i[p][reg] = yr * tws[reg] + yi * twc[reg];
        }
    }
    // LDS2 [m2][m1][o3]; pos = m1*16+o3, swizzle pos ^= (m2>>2)<<4 ^ (m2&3)<<2.
#pragma unroll
    for (int reg = 0; reg < 4; ++reg) {
        const int m2 = 4 * g + reg;
#pragma unroll
        for (int p = 0; p < 4; ++p) {
            const int spos = (((4 * w + p) * 16 + c) ^ (g << 4)) ^ (reg << 2);
            const int half = m2 * 256 + spos;
            *(unsigned short*)(smem + 16384 + half * 2) = h16(s2r[p][reg]);
            *(unsigned short*)(smem + 24576 + half * 2) = h16(s2i[p][reg]);
        }
    }
    __syncthreads();

    // ================= stage 3: V^T[m2][n3] = sum_o3 U^T[m2][o3] M^T[o3][n3] ==
    // A rows = m2 = c, k = o3 = 4g+jj (contiguous b64), tile = m1 = 4w+p
    FragU Aup[4];
#pragma unroll
    for (int p = 0; p < 4; ++p) {
        const int spos = ((((4 * w + p) * 16 + 4 * g) ^ (((c >> 2) & 3) << 4))
                          ^ ((c & 3) << 2));
        const int half = c * 256 + spos;
        const uint2 hr = *(const uint2*)(smem + 16384 + half * 2);
        const uint2 hi = *(const uint2*)(smem + 24576 + half * 2);
        Aup[p].u[0] = hr.x; Aup[p].u[1] = hr.y;
        Aup[p].u[2] = hi.x; Aup[p].u[3] = hi.y;
    }
    __syncthreads();   // all LDS2 reads done before F overlays it

    f32x4 vR[4], vI[4];
#pragma unroll
    for (int p = 0; p < 4; ++p) {
        vR[p] = MFMA(Aup[p], BMr, zero);
        vI[p] = MFMA(Aup[p], BMi, zero);
    }

    // F[n3][inner] float2, inner = (m2*16 + m1) ^ ((n3 & 7) << 1); n3 = c.
    {
        const int swz = (c & 7) << 1;
#pragma unroll
        for (int reg = 0; reg < 4; ++reg) {
            const int i0 = (((4 * g + reg) * 16 + 4 * w) ^ swz);
            const int i1 = (((4 * g + reg) * 16 + 4 * w + 2) ^ swz);
            const f32x4 a = {vR[0][reg], vI[0][reg], vR[1][reg], vI[1][reg]};
            const f32x4 b = {vR[2][reg], vI[2][reg], vR[3][reg], vI[3][reg]};
            *(f32x4*)(smem + (size_t)(c * 256 + i0) * 8) = a;
            *(f32x4*)(smem + (size_t)(c * 256 + i1) * 8) = b;
        }
    }
    __syncthreads();

    // coalesced nontemporal store: 2 complex (16B) per lane per iter
    f32x4* __restrict__ og4 = (f32x4*)out;
#pragma unroll
    for (int it = 0; it < 8; ++it) {
        const int jr = 2 * it + (t >> 7);
        const int u  = (t & 127) * 2;
        const int is = u ^ ((jr & 7) << 1);
        const f32x4 v = *(const f32x4*)(smem + (size_t)(jr * 256 + is) * 8);
        __builtin_nontemporal_store(v, &og4[(base + (size_t)(jr * 256 + u)) >> 1]);
    }
}

extern "C" void kernel_launch(void* const* d_in, const int* in_sizes, int n_in,
                              void* d_out, int out_size, void* d_ws, size_t ws_size,
                              hipStream_t stream)
{
    const float* xre = (const float*)d_in[0];
    const float* xim = (const float*)d_in[1];
    const float* m16 = (const float*)d_in[5];   // (H,16,16,2) fp32
    const int H  = in_sizes[5] / 512;
    const int BH = in_sizes[0] / 4096;
    fft4096_mfma<<<dim3(BH), dim3(256), 0, stream>>>(
        xre, xim, m16, (float*)d_out, H);
}